// Round 11
// baseline (204.857 us; speedup 1.0000x reference)
//
#include <hip/hip_runtime.h>
#include <stdint.h>

#define B_ 8
#define C_ 256
#define N_ 2048
#define HC 128

typedef float f32x4 __attribute__((ext_vector_type(4)));
typedef float f32x16 __attribute__((ext_vector_type(16)));
typedef short s16x8 __attribute__((ext_vector_type(8)));

__device__ __forceinline__ unsigned short f2bf(float f){
  union { float f; unsigned u; } v; v.f = f;
  unsigned r = v.u + 0x7FFF + ((v.u >> 16) & 1u);
  return (unsigned short)(r >> 16);
}
__device__ __forceinline__ float bf2f(unsigned short u){
  union { unsigned u; float f; } v; v.u = ((unsigned)u) << 16;
  return v.f;
}
__device__ __forceinline__ void gload_lds16(const void* g, void* l){
  __builtin_amdgcn_global_load_lds(
      (const __attribute__((address_space(1))) unsigned int*)g,
      (__attribute__((address_space(3))) unsigned int*)l, 16, 0, 0);
}

// ---------------- prep: weights -> bf16, BN affine fold ----------------
struct PrepArgs {
  const float *s0,*s1,*s2,*s3,*s4,*s5;
  unsigned short *d0,*d1,*d2,*d3,*d4,*d5;
  const float *b1,*g1,*be1,*m1,*v1;
  const float *b2,*g2,*be2,*m2,*v2;
  float *sc1,*sh1,*sc2,*sh2;
};

__global__ __launch_bounds__(256) void k_prep(PrepArgs a){
  int gid = blockIdx.x*256 + threadIdx.x;
  const int S0=65536, S1=131072, S2=196608, S3=229376, S4=245760, S5=278528;
  if (gid < S0)      a.d0[gid]    = f2bf(a.s0[gid]);
  else if (gid < S1) a.d1[gid-S0] = f2bf(a.s1[gid-S0]);
  else if (gid < S2) a.d2[gid-S1] = f2bf(a.s2[gid-S1]);
  else if (gid < S3) a.d3[gid-S2] = f2bf(a.s3[gid-S2]);
  else if (gid < S4) a.d4[gid-S3] = f2bf(a.s4[gid-S3]);
  else if (gid < S5) a.d5[gid-S4] = f2bf(a.s5[gid-S4]);
  else if (gid < S5+128){
    int o = gid - S5;
    float inv = a.g1[o] * rsqrtf(a.v1[o] + 1e-5f);
    a.sc1[o] = inv;
    a.sh1[o] = a.b1[o]*inv + a.be1[o] - a.m1[o]*inv;
  } else if (gid < S5+256){
    int o = gid - S5 - 128;
    float inv = a.g2[o] * rsqrtf(a.v2[o] + 1e-5f);
    a.sc2[o] = inv;
    a.sh2[o] = a.b2[o]*inv + a.be2[o] - a.m2[o]*inv;
  }
}

// ---------------- fused: x-transpose + QKV GEMM ----------------
// Stage x[b][:, nb..nb+64] transposed->bf16 into Alds via an f32 LDS tile,
// then run the three weight GEMMs off the single staged A-tile.
__global__ __launch_bounds__(256) void k_qkv(
    const float* __restrict__ x,
    const unsigned short* __restrict__ wqb, const unsigned short* __restrict__ wkb,
    const unsigned short* __restrict__ wvb,
    const float* __restrict__ bq, const float* __restrict__ bk, const float* __restrict__ bv,
    unsigned short* __restrict__ Qn, unsigned short* __restrict__ Kn,
    unsigned short* __restrict__ Vc)
{
  __shared__ unsigned short Alds[64][256];
  __shared__ unsigned short Tlds[64][260];
  int b = blockIdx.y, nt = blockIdx.x;
  int nb = nt*64;
  const float* xb = x + (size_t)b*C_*N_;
  int tid = threadIdx.x;
  // prologue: 4 c-subtiles of 64: x -> f32 LDS transpose -> Alds bf16 (swizzled)
  float* Tf = (float*)&Tlds[0][0];   // [64][65]
  int tn = tid & 63, tq = tid >> 6;
  for (int c0 = 0; c0 < 256; c0 += 64){
    #pragma unroll
    for (int cc = tq; cc < 64; cc += 4)
      Tf[tn*65 + cc] = xb[(size_t)(c0+cc)*N_ + nb + tn];
    __syncthreads();
    #pragma unroll
    for (int nl = tq; nl < 64; nl += 4){
      int c = c0 + tn;
      Alds[nl][c ^ ((nl&7)<<3)] = f2bf(Tf[nl*65 + tn]);
    }
    __syncthreads();
  }
  int w = tid >> 6, l = tid & 63, lr = l & 15, lq = l >> 4;
  const unsigned short* Ws[3] = {wqb, wkb, wvb};
  const float* bs[3] = {bq, bk, bv};
  f32x4 zero = {0.f,0.f,0.f,0.f};
  for (int z = 0; z < 3; z++){
    const unsigned short* W = Ws[z];
    const float* bias = bs[z];
    f32x4 acc[16];
    #pragma unroll
    for (int i=0;i<16;i++) acc[i] = zero;
    #pragma unroll
    for (int ks = 0; ks < 8; ks++){
      s16x8 a = *(const s16x8*)&Alds[16*w + lr][(32*ks + 8*lq) ^ ((lr&7)<<3)];
      #pragma unroll
      for (int ct = 0; ct < 16; ct++){
        s16x8 bw = *(const s16x8*)&W[(size_t)(16*ct + lr)*C_ + 32*ks + 8*lq];
        acc[ct] = __builtin_amdgcn_mfma_f32_16x16x32_bf16(a, bw, acc[ct], 0, 0, 0);
      }
    }
    if (z < 2){
      unsigned short* ob = (z==0 ? Qn : Kn) + ((size_t)b*N_ + nb)*C_;
      #pragma unroll
      for (int ct = 0; ct < 16; ct++){
        int o = 16*ct + lr;
        float bi = bias[o];
        #pragma unroll
        for (int r = 0; r < 4; r++){
          int row = 16*w + 4*lq + r;
          ob[(size_t)row*C_ + o] = f2bf(acc[ct][r] + bi);
        }
      }
    } else {
      __syncthreads();
      #pragma unroll
      for (int ct = 0; ct < 16; ct++){
        int o = 16*ct + lr;
        float bi = bias[o];
        #pragma unroll
        for (int r = 0; r < 4; r++)
          Tlds[16*w + 4*lq + r][o] = f2bf(acc[ct][r] + bi);
      }
      __syncthreads();
      unsigned short* vb = Vc + (size_t)b*C_*N_;
      int j = tid & 63, o0 = tid >> 6;
      #pragma unroll
      for (int o = o0; o < 256; o += 4)
        vb[(size_t)o*N_ + nb + j] = Tlds[j][o];
    }
  }
}

// ---------------- attention: swapped-QK^T 32x32, counted-vmcnt beta pipeline ----
// grid 512 x 256 thr = 2 blocks/CU. beta triple-buffered in LDS, prefetched at
// DISTANCE 2 via global_load_lds; barrier B waits vmcnt(4) (raw s_barrier) so
// the freshest beta prefetch is NEVER drained -- removes the per-tile
// HBM-latency serialization that capped R10. K/V single-buffered (L2-hot),
// staged between barrier A and B. Compute math identical to R10 (verified).
__global__ __launch_bounds__(256, 2) void k_attn(
    const unsigned short* __restrict__ Qn, const unsigned short* __restrict__ Kn,
    const unsigned short* __restrict__ Vc, const float* __restrict__ beta,
    unsigned short* __restrict__ Opb, float* __restrict__ Ls)
{
  __shared__ __align__(16) char smem[81920];
  unsigned short* Klds = (unsigned short*)smem;             // 16 KB  [32 r][256 c]
  unsigned short* Vt   = (unsigned short*)(smem + 16384);   // 16 KB  [256 c][32 m]
  float*          Bl   = (float*)(smem + 32768);            // 3x16KB [128 q][32 m]
  const int tid = threadIdx.x;
  const int bid = blockIdx.x;
  const int b = bid & 7;
  const int jj = bid >> 3;
  const int nt = jj & 15, mh = jj >> 4;
  const int nb = nt*128;
  const unsigned short* Qb = Qn + (size_t)b*N_*C_;
  const unsigned short* Kb = Kn + (size_t)b*N_*C_;
  const unsigned short* Vb = Vc + (size_t)b*C_*N_;
  const float* betab = beta + (size_t)b*N_*N_;
  const int w = tid >> 6, lane = tid & 63, q31 = lane & 31, hi = lane >> 5;
  const int qr = nb + 32*w + q31;
  const int wbase = (tid & ~63) * 16;

  s16x8 qf[16];
  {
    const unsigned short* qp = Qb + (size_t)qr*C_ + 8*hi;
    #pragma unroll
    for (int ks = 0; ks < 16; ks++)
      qf[ks] = *(const s16x8*)&qp[16*ks];
  }
  f32x16 oacc[8];
  #pragma unroll
  for (int i=0;i<8;i++)
    #pragma unroll
    for (int e=0;e<16;e++) oacc[i][e] = 0.f;
  float psum = 0.f;

#define STAGEK(MB) { \
  _Pragma("unroll") \
  for (int rr=0; rr<4; rr++){ \
    const int o_ = rr*4096 + tid*16; \
    const int row_ = o_ >> 9; \
    const int slot_ = (o_ >> 4) & 31; \
    gload_lds16(Kb + (size_t)((MB)+row_)*C_ + ((slot_ ^ (row_&31))<<3), \
                (char*)Klds + rr*4096 + wbase); } }
#define STAGEV(MB) { \
  _Pragma("unroll") \
  for (int rr=0; rr<4; rr++){ \
    const int o_ = rr*4096 + tid*16; \
    const int c_ = o_ >> 6; \
    const int slot_ = (o_ >> 4) & 3; \
    gload_lds16(Vb + (size_t)c_*N_ + (MB) + ((slot_ ^ (c_&3))<<3), \
                (char*)Vt + rr*4096 + wbase); } }
#define STAGEB(BUF, MB) { \
  _Pragma("unroll") \
  for (int rr=0; rr<4; rr++){ \
    const int o_ = rr*4096 + tid*16; \
    const int row_ = o_ >> 7; \
    const int g_ = (o_ >> 4) & 7; \
    gload_lds16(betab + (size_t)(nb+row_)*N_ + (MB) + ((g_ ^ (row_&7))<<2), \
                (char*)Bl + (BUF)*16384 + rr*4096 + wbase); } }

  // prologue: K/V(0), beta(0), beta(1); wait all but the 4 beta(1) loads
  STAGEK(mh*512)
  STAGEV(mh*512)
  STAGEB(0, mh*512)
  STAGEB(1, mh*512 + 32)
  asm volatile("s_waitcnt vmcnt(4)" ::: "memory");
  __builtin_amdgcn_s_barrier();
  __builtin_amdgcn_sched_barrier(0);

  for (int mt = 0; mt < 16; mt++){
    const int mb = mh*512 + mt*32;
    const float* Bp = Bl + (mt % 3) * 4096;
    // beta(mt) from LDS (arrived; forced by prior vmcnt)
    f32x4 bv[4];
    #pragma unroll
    for (int j=0;j<4;j++)
      bv[j] = *(const f32x4*)&Bp[(32*w + q31)*32 + (((2*j+hi) ^ (q31&7))<<2)];
    // S^T = K . Q
    f32x16 sacc;
    #pragma unroll
    for (int e=0;e<16;e++) sacc[e] = 0.f;
    __builtin_amdgcn_s_setprio(1);
    #pragma unroll
    for (int ks=0; ks<16; ks++){
      const s16x8 kf = *(const s16x8*)
          &Klds[q31*256 + (((2*ks + hi) ^ q31) << 3)];
      sacc = __builtin_amdgcn_mfma_f32_32x32x16_bf16(kf, qf[ks], sacc, 0, 0, 0);
    }
    __builtin_amdgcn_s_setprio(0);
    float p[16];
    #pragma unroll
    for (int r=0;r<16;r++){
      p[r] = __expf(sacc[r] * bv[r>>2][r&3]);
      psum += p[r];
    }
    __builtin_amdgcn_s_setprio(1);
    #pragma unroll
    for (int u=0; u<2; u++){
      unsigned X  = ((unsigned)f2bf(p[8*u+1])<<16) | f2bf(p[8*u+0]);
      unsigned X2 = ((unsigned)f2bf(p[8*u+3])<<16) | f2bf(p[8*u+2]);
      unsigned Y  = ((unsigned)f2bf(p[8*u+5])<<16) | f2bf(p[8*u+4]);
      unsigned Y2 = ((unsigned)f2bf(p[8*u+7])<<16) | f2bf(p[8*u+6]);
      unsigned Xs  = (unsigned)__shfl_xor((int)X,  32, 64);
      unsigned X2s = (unsigned)__shfl_xor((int)X2, 32, 64);
      unsigned Ys  = (unsigned)__shfl_xor((int)Y,  32, 64);
      unsigned Y2s = (unsigned)__shfl_xor((int)Y2, 32, 64);
      union { unsigned uu[4]; s16x8 v; } pa;
      pa.uu[0] = hi ? Ys  : X;
      pa.uu[1] = hi ? Y2s : X2;
      pa.uu[2] = hi ? Y   : Xs;
      pa.uu[3] = hi ? Y2  : X2s;
      #pragma unroll
      for (int ct=0; ct<8; ct++){
        const int c = 32*ct + q31;
        const s16x8 vf = *(const s16x8*)
            &Vt[c*32 + (((2*u + hi) ^ (c&3)) << 3)];
        oacc[ct] = __builtin_amdgcn_mfma_f32_32x32x16_bf16(pa.v, vf, oacc[ct], 0,0,0);
      }
    }
    __builtin_amdgcn_s_setprio(0);
    // barrier A: all LDS reads of tile mt done (leave VMEM queue untouched)
    asm volatile("s_waitcnt lgkmcnt(0)" ::: "memory");
    __builtin_amdgcn_s_barrier();
    __builtin_amdgcn_sched_barrier(0);
    if (mt + 1 < 16){
      STAGEK(mb + 32)
      STAGEV(mb + 32)
      if (mt + 2 < 16){
        STAGEB((mt + 2) % 3, mb + 64)
        // wait K/V(t+1)+beta(t+1); leave the 4 beta(t+2) loads in flight
        asm volatile("s_waitcnt vmcnt(4)" ::: "memory");
      } else {
        asm volatile("s_waitcnt vmcnt(0)" ::: "memory");
      }
      __builtin_amdgcn_s_barrier();
      __builtin_amdgcn_sched_barrier(0);
    }
  }
#undef STAGEK
#undef STAGEV
#undef STAGEB

  psum += __shfl_xor(psum, 32, 64);
  unsigned short* Ob = Opb + ((size_t)mh*8 + b)*(size_t)N_*C_;
  #pragma unroll
  for (int ct=0; ct<8; ct++){
    const int c = 32*ct + q31;
    #pragma unroll
    for (int r=0;r<16;r++){
      const int qo = nb + 32*w + (r&3) + 8*(r>>2) + 4*hi;
      Ob[(size_t)qo*C_ + c] = f2bf(oacc[ct][r]);
    }
  }
  if (hi == 0){
    float* Lb = Ls + ((size_t)mh*8 + b)*N_;
    Lb[qr] = psum;
  }
}

// ---------------- fused MLP: merge+normalize -> conv1(BN,ReLU) -> conv2(BN,ReLU)
// -> conv3(+bias) -> residual add, all through LDS (overlaid phases).
__global__ __launch_bounds__(256) void k_mlpf(
    const unsigned short* __restrict__ Opb, const float* __restrict__ Ls,
    const unsigned short* __restrict__ W1, const float* __restrict__ sc1,
    const float* __restrict__ sh1,
    const unsigned short* __restrict__ W2, const float* __restrict__ sc2,
    const float* __restrict__ sh2,
    const unsigned short* __restrict__ W3, const float* __restrict__ b3,
    const float* __restrict__ x, float* __restrict__ out)
{
  __shared__ __align__(16) char smem[65792];
  unsigned short* Alds = (unsigned short*)smem;            // [64][256] @0..32768 (phase1)
  unsigned short* H2   = (unsigned short*)(smem + 33024);  // [64][128] @33024..49408
  unsigned short* H1   = (unsigned short*)(smem + 49408);  // [64][128] @49408..65792
  float*          Dlds = (float*)smem;                     // [64][129] @0..33024 (phase3)
  int b = blockIdx.y, nt = blockIdx.x, nb = nt*64;
  int tid = threadIdx.x;
  const size_t PS = (size_t)8*N_*C_;
  // merge 4 partials + normalize -> Alds (swizzled bf16)
  for (int i = tid; i < 64*32; i += 256){
    int r = i >> 5, cv = i & 31;
    int row = nb + r;
    float ls = Ls[(size_t)b*N_ + row] + Ls[(size_t)(8+b)*N_ + row]
             + Ls[(size_t)(16+b)*N_ + row] + Ls[(size_t)(24+b)*N_ + row];
    float inv = 1.f / ls;
    size_t base = ((size_t)b*N_ + row)*C_ + cv*8;
    float a8[8] = {0.f,0.f,0.f,0.f,0.f,0.f,0.f,0.f};
    #pragma unroll
    for (int m=0;m<4;m++){
      s16x8 v = *(const s16x8*)&Opb[(size_t)m*PS + base];
      #pragma unroll
      for (int j=0;j<8;j++) a8[j] += bf2f((unsigned short)v[j]);
    }
    s16x8 o;
    #pragma unroll
    for (int j=0;j<8;j++) o[j] = (short)f2bf(a8[j] * inv);
    *(s16x8*)&Alds[r*256 + ((cv*8) ^ ((r&7)<<3))] = o;
  }
  __syncthreads();
  int w = tid >> 6, l = tid & 63, lr = l & 15, lq = l >> 4;
  f32x4 zero = {0.f,0.f,0.f,0.f};
  // GEMM1: msg(256) -> h1(128), BN+ReLU, to H1 LDS
  {
    f32x4 acc[8];
    #pragma unroll
    for (int i=0;i<8;i++) acc[i] = zero;
    #pragma unroll
    for (int ks = 0; ks < 8; ks++){
      s16x8 a = *(const s16x8*)&Alds[(16*w + lr)*256 + ((32*ks + 8*lq) ^ ((lr&7)<<3))];
      #pragma unroll
      for (int ct = 0; ct < 8; ct++){
        s16x8 bw = *(const s16x8*)&W1[(size_t)(16*ct + lr)*C_ + 32*ks + 8*lq];
        acc[ct] = __builtin_amdgcn_mfma_f32_16x16x32_bf16(a, bw, acc[ct], 0, 0, 0);
      }
    }
    __syncthreads();   // Alds reads done (Dlds overlays it later, H1 write now)
    #pragma unroll
    for (int ct = 0; ct < 8; ct++){
      int o = 16*ct + lr;
      float s_ = sc1[o], h_ = sh1[o];
      #pragma unroll
      for (int r = 0; r < 4; r++){
        int row = 16*w + 4*lq + r;
        H1[row*128 + (o ^ ((row&7)<<3))] = f2bf(fmaxf(acc[ct][r]*s_ + h_, 0.f));
      }
    }
  }
  __syncthreads();
  // GEMM2: h1(128) -> h2(128), BN+ReLU, to H2 LDS
  {
    f32x4 acc[8];
    #pragma unroll
    for (int i=0;i<8;i++) acc[i] = zero;
    #pragma unroll
    for (int ks = 0; ks < 4; ks++){
      s16x8 a = *(const s16x8*)&H1[(16*w + lr)*128 + ((32*ks + 8*lq) ^ ((lr&7)<<3))];
      #pragma unroll
      for (int ct = 0; ct < 8; ct++){
        s16x8 bw = *(const s16x8*)&W2[(size_t)(16*ct + lr)*HC + 32*ks + 8*lq];
        acc[ct] = __builtin_amdgcn_mfma_f32_16x16x32_bf16(a, bw, acc[ct], 0, 0, 0);
      }
    }
    __syncthreads();
    #pragma unroll
    for (int ct = 0; ct < 8; ct++){
      int o = 16*ct + lr;
      float s_ = sc2[o], h_ = sh2[o];
      #pragma unroll
      for (int r = 0; r < 4; r++){
        int row = 16*w + 4*lq + r;
        H2[row*128 + (o ^ ((row&7)<<3))] = f2bf(fmaxf(acc[ct][r]*s_ + h_, 0.f));
      }
    }
  }
  __syncthreads();
  // GEMM3: h2(128) -> d(256) + b3; residual add via two Dlds half-tiles
  f32x4 acc[16];
  #pragma unroll
  for (int i=0;i<16;i++) acc[i] = zero;
  #pragma unroll
  for (int ks = 0; ks < 4; ks++){
    s16x8 a = *(const s16x8*)&H2[(16*w + lr)*128 + ((32*ks + 8*lq) ^ ((lr&7)<<3))];
    #pragma unroll
    for (int ct = 0; ct < 16; ct++){
      s16x8 bw = *(const s16x8*)&W3[(size_t)(16*ct + lr)*HC + 32*ks + 8*lq];
      acc[ct] = __builtin_amdgcn_mfma_f32_16x16x32_bf16(a, bw, acc[ct], 0, 0, 0);
    }
  }
  const float* xb = x + (size_t)b*C_*N_;
  float* ob = out + (size_t)b*C_*N_;
  int j = tid & 63, o0 = tid >> 6;
  #pragma unroll
  for (int half = 0; half < 2; half++){
    __syncthreads();
    #pragma unroll
    for (int ct = 8*half; ct < 8*half+8; ct++){
      int o = 16*ct + lr;
      float bi = b3[o];
      #pragma unroll
      for (int r = 0; r < 4; r++){
        int row = 16*w + 4*lq + r;
        Dlds[row*129 + (o - 128*half)] = acc[ct][r] + bi;
      }
    }
    __syncthreads();
    for (int o = 128*half + o0; o < 128*half + 128; o += 4)
      ob[(size_t)o*N_ + nb + j] = xb[(size_t)o*N_ + nb + j]
                                + Dlds[j*129 + (o - 128*half)];
  }
}

extern "C" void kernel_launch(void* const* d_in, const int* in_sizes, int n_in,
                              void* d_out, int out_size, void* d_ws, size_t ws_size,
                              hipStream_t stream)
{
  const float* x    = (const float*)d_in[0];
  const float* beta = (const float*)d_in[1];
  const float* wq = (const float*)d_in[2];  const float* bq = (const float*)d_in[3];
  const float* wk = (const float*)d_in[4];  const float* bk = (const float*)d_in[5];
  const float* wv = (const float*)d_in[6];  const float* bv = (const float*)d_in[7];
  const float* w1 = (const float*)d_in[8];  const float* b1 = (const float*)d_in[9];
  const float* g1 = (const float*)d_in[10]; const float* be1= (const float*)d_in[11];
  const float* m1 = (const float*)d_in[12]; const float* v1 = (const float*)d_in[13];
  const float* w2 = (const float*)d_in[14]; const float* b2 = (const float*)d_in[15];
  const float* g2 = (const float*)d_in[16]; const float* be2= (const float*)d_in[17];
  const float* m2 = (const float*)d_in[18]; const float* v2 = (const float*)d_in[19];
  const float* w3 = (const float*)d_in[20]; const float* b3 = (const float*)d_in[21];

  char* p = (char*)d_ws;
  auto alloc = [&](size_t n){ char* r = p; p += (n + 255) & ~(size_t)255; return r; };
  unsigned short* Qn  = (unsigned short*)alloc((size_t)B_*N_*C_*2);
  unsigned short* Kn  = (unsigned short*)alloc((size_t)B_*N_*C_*2);
  unsigned short* Vc  = (unsigned short*)alloc((size_t)B_*N_*C_*2);
  unsigned short* Opb = (unsigned short*)alloc((size_t)4*B_*N_*C_*2);
  float* Ls = (float*)alloc((size_t)4*B_*N_*4);
  unsigned short* wqb = (unsigned short*)alloc(65536*2);
  unsigned short* wkb = (unsigned short*)alloc(65536*2);
  unsigned short* wvb = (unsigned short*)alloc(65536*2);
  unsigned short* w1b = (unsigned short*)alloc(32768*2);
  unsigned short* w2b = (unsigned short*)alloc(16384*2);
  unsigned short* w3b = (unsigned short*)alloc(32768*2);
  float* sc1 = (float*)alloc(128*4);
  float* sh1 = (float*)alloc(128*4);
  float* sc2 = (float*)alloc(128*4);
  float* sh2 = (float*)alloc(128*4);

  PrepArgs pa;
  pa.s0 = wq; pa.s1 = wk; pa.s2 = wv; pa.s3 = w1; pa.s4 = w2; pa.s5 = w3;
  pa.d0 = wqb; pa.d1 = wkb; pa.d2 = wvb; pa.d3 = w1b; pa.d4 = w2b; pa.d5 = w3b;
  pa.b1 = b1; pa.g1 = g1; pa.be1 = be1; pa.m1 = m1; pa.v1 = v1;
  pa.b2 = b2; pa.g2 = g2; pa.be2 = be2; pa.m2 = m2; pa.v2 = v2;
  pa.sc1 = sc1; pa.sh1 = sh1; pa.sc2 = sc2; pa.sh2 = sh2;

  k_prep<<<dim3(1089), dim3(256), 0, stream>>>(pa);
  k_qkv<<<dim3(32, 8), dim3(256), 0, stream>>>(x, wqb, wkb, wvb, bq, bk, bv, Qn, Kn, Vc);
  k_attn<<<dim3(512), dim3(256), 0, stream>>>(Qn, Kn, Vc, beta, Opb, Ls);
  k_mlpf<<<dim3(32, 8), dim3(256), 0, stream>>>(Opb, Ls, w1b, sc1, sh1,
                                                w2b, sc2, sh2, w3b, b3,
                                                x, (float*)d_out);
}

// Round 12
// 183.167 us; speedup vs baseline: 1.1184x; 1.1184x over previous
//
#include <hip/hip_runtime.h>
#include <stdint.h>

#define B_ 8
#define C_ 256
#define N_ 2048
#define HC 128

typedef float f32x4 __attribute__((ext_vector_type(4)));
typedef float f32x16 __attribute__((ext_vector_type(16)));
typedef short s16x8 __attribute__((ext_vector_type(8)));

__device__ __forceinline__ unsigned short f2bf(float f){
  union { float f; unsigned u; } v; v.f = f;
  unsigned r = v.u + 0x7FFF + ((v.u >> 16) & 1u);
  return (unsigned short)(r >> 16);
}
__device__ __forceinline__ float bf2f(unsigned short u){
  union { unsigned u; float f; } v; v.u = ((unsigned)u) << 16;
  return v.f;
}
__device__ __forceinline__ void gload_lds16(const void* g, void* l){
  __builtin_amdgcn_global_load_lds(
      (const __attribute__((address_space(1))) unsigned int*)g,
      (__attribute__((address_space(3))) unsigned int*)l, 16, 0, 0);
}

// ---------------- prep: weights -> bf16, BN affine fold ----------------
struct PrepArgs {
  const float *s0,*s1,*s2,*s3,*s4,*s5;
  unsigned short *d0,*d1,*d2,*d3,*d4,*d5;
  const float *b1,*g1,*be1,*m1,*v1;
  const float *b2,*g2,*be2,*m2,*v2;
  float *sc1,*sh1,*sc2,*sh2;
};

__global__ __launch_bounds__(256) void k_prep(PrepArgs a){
  int gid = blockIdx.x*256 + threadIdx.x;
  const int S0=65536, S1=131072, S2=196608, S3=229376, S4=245760, S5=278528;
  if (gid < S0)      a.d0[gid]    = f2bf(a.s0[gid]);
  else if (gid < S1) a.d1[gid-S0] = f2bf(a.s1[gid-S0]);
  else if (gid < S2) a.d2[gid-S1] = f2bf(a.s2[gid-S1]);
  else if (gid < S3) a.d3[gid-S2] = f2bf(a.s3[gid-S2]);
  else if (gid < S4) a.d4[gid-S3] = f2bf(a.s4[gid-S3]);
  else if (gid < S5) a.d5[gid-S4] = f2bf(a.s5[gid-S4]);
  else if (gid < S5+128){
    int o = gid - S5;
    float inv = a.g1[o] * rsqrtf(a.v1[o] + 1e-5f);
    a.sc1[o] = inv;
    a.sh1[o] = a.b1[o]*inv + a.be1[o] - a.m1[o]*inv;
  } else if (gid < S5+256){
    int o = gid - S5 - 128;
    float inv = a.g2[o] * rsqrtf(a.v2[o] + 1e-5f);
    a.sc2[o] = inv;
    a.sh2[o] = a.b2[o]*inv + a.be2[o] - a.m2[o]*inv;
  }
}

// ---------------- fused: x-transpose + QKV GEMM ----------------
__global__ __launch_bounds__(256) void k_qkv(
    const float* __restrict__ x,
    const unsigned short* __restrict__ wqb, const unsigned short* __restrict__ wkb,
    const unsigned short* __restrict__ wvb,
    const float* __restrict__ bq, const float* __restrict__ bk, const float* __restrict__ bv,
    unsigned short* __restrict__ Qn, unsigned short* __restrict__ Kn,
    unsigned short* __restrict__ Vc)
{
  __shared__ unsigned short Alds[64][256];
  __shared__ unsigned short Tlds[64][260];
  int b = blockIdx.y, nt = blockIdx.x;
  int nb = nt*64;
  const float* xb = x + (size_t)b*C_*N_;
  int tid = threadIdx.x;
  float* Tf = (float*)&Tlds[0][0];   // [64][65]
  int tn = tid & 63, tq = tid >> 6;
  for (int c0 = 0; c0 < 256; c0 += 64){
    #pragma unroll
    for (int cc = tq; cc < 64; cc += 4)
      Tf[tn*65 + cc] = xb[(size_t)(c0+cc)*N_ + nb + tn];
    __syncthreads();
    #pragma unroll
    for (int nl = tq; nl < 64; nl += 4){
      int c = c0 + tn;
      Alds[nl][c ^ ((nl&7)<<3)] = f2bf(Tf[nl*65 + tn]);
    }
    __syncthreads();
  }
  int w = tid >> 6, l = tid & 63, lr = l & 15, lq = l >> 4;
  const unsigned short* Ws[3] = {wqb, wkb, wvb};
  const float* bs[3] = {bq, bk, bv};
  f32x4 zero = {0.f,0.f,0.f,0.f};
  for (int z = 0; z < 3; z++){
    const unsigned short* W = Ws[z];
    const float* bias = bs[z];
    f32x4 acc[16];
    #pragma unroll
    for (int i=0;i<16;i++) acc[i] = zero;
    #pragma unroll
    for (int ks = 0; ks < 8; ks++){
      s16x8 a = *(const s16x8*)&Alds[16*w + lr][(32*ks + 8*lq) ^ ((lr&7)<<3)];
      #pragma unroll
      for (int ct = 0; ct < 16; ct++){
        s16x8 bw = *(const s16x8*)&W[(size_t)(16*ct + lr)*C_ + 32*ks + 8*lq];
        acc[ct] = __builtin_amdgcn_mfma_f32_16x16x32_bf16(a, bw, acc[ct], 0, 0, 0);
      }
    }
    if (z < 2){
      unsigned short* ob = (z==0 ? Qn : Kn) + ((size_t)b*N_ + nb)*C_;
      #pragma unroll
      for (int ct = 0; ct < 16; ct++){
        int o = 16*ct + lr;
        float bi = bias[o];
        #pragma unroll
        for (int r = 0; r < 4; r++){
          int row = 16*w + 4*lq + r;
          ob[(size_t)row*C_ + o] = f2bf(acc[ct][r] + bi);
        }
      }
    } else {
      __syncthreads();
      #pragma unroll
      for (int ct = 0; ct < 16; ct++){
        int o = 16*ct + lr;
        float bi = bias[o];
        #pragma unroll
        for (int r = 0; r < 4; r++)
          Tlds[16*w + 4*lq + r][o] = f2bf(acc[ct][r] + bi);
      }
      __syncthreads();
      unsigned short* vb = Vc + (size_t)b*C_*N_;
      int j = tid & 63, o0 = tid >> 6;
      #pragma unroll
      for (int o = o0; o < 256; o += 4)
        vb[(size_t)o*N_ + nb + j] = Tlds[j][o];
    }
  }
}

// ---------------- attention: R10 pipeline + 64-wide V tiles (4-way not 8-way
// bank conflicts, per R8 measurement). grid 512 x 256 thr = 2 blocks/CU.
// beta double-buffered in LDS, ISSUED AT TOP OF COMPUTE (full tile of flight);
// K staged per tile, V staged in 64-m pairs every other tile (both L2-hot).
// One lgkmcnt barrier + one __syncthreads per tile. LDS 80KB.
__global__ __launch_bounds__(256, 2) void k_attn(
    const unsigned short* __restrict__ Qn, const unsigned short* __restrict__ Kn,
    const unsigned short* __restrict__ Vc, const float* __restrict__ beta,
    unsigned short* __restrict__ Opb, float* __restrict__ Ls)
{
  __shared__ __align__(16) char smem[81920];
  unsigned short* Klds = (unsigned short*)smem;             // 16 KB [32 r][256 c]
  unsigned short* Vt   = (unsigned short*)(smem + 16384);   // 32 KB [256 c][64 m]
  float*          Bl   = (float*)(smem + 49152);            // 2x16KB [128 q][32 m]
  const int tid = threadIdx.x;
  const int bid = blockIdx.x;
  const int b = bid & 7;
  const int jj = bid >> 3;
  const int nt = jj & 15, mh = jj >> 4;
  const int nb = nt*128;
  const unsigned short* Qb = Qn + (size_t)b*N_*C_;
  const unsigned short* Kb = Kn + (size_t)b*N_*C_;
  const unsigned short* Vb = Vc + (size_t)b*C_*N_;
  const float* betab = beta + (size_t)b*N_*N_;
  const int w = tid >> 6, lane = tid & 63, q31 = lane & 31, hi = lane >> 5;
  const int qr = nb + 32*w + q31;
  const int wbase = (tid & ~63) * 16;

  s16x8 qf[16];
  {
    const unsigned short* qp = Qb + (size_t)qr*C_ + 8*hi;
    #pragma unroll
    for (int ks = 0; ks < 16; ks++)
      qf[ks] = *(const s16x8*)&qp[16*ks];
  }
  f32x16 oacc[8];
  #pragma unroll
  for (int i=0;i<8;i++)
    #pragma unroll
    for (int e=0;e<16;e++) oacc[i][e] = 0.f;
  float psum = 0.f;

// K: LDS[row][slot] = K[mb+row][(slot^row)*8 .. +8)   (32 rows x 32 slots)
#define STAGEK(MB) { \
  _Pragma("unroll") \
  for (int rr=0; rr<4; rr++){ \
    const int o_ = rr*4096 + tid*16; \
    const int row_ = o_ >> 9; \
    const int slot_ = (o_ >> 4) & 31; \
    gload_lds16(Kb + (size_t)((MB)+row_)*C_ + ((slot_ ^ (row_&31))<<3), \
                (char*)Klds + rr*4096 + wbase); } }
// V (64-wide pair): LDS[c][slot] = V[c][(MB) + (slot^(c&7))*8 .. +8)  (256c x 8 slots)
#define STAGEV(MB) { \
  _Pragma("unroll") \
  for (int rr=0; rr<8; rr++){ \
    const int o_ = rr*4096 + tid*16; \
    const int c_ = o_ >> 7; \
    const int slot_ = (o_ >> 4) & 7; \
    gload_lds16(Vb + (size_t)c_*N_ + (MB) + ((slot_ ^ (c_&7))<<3), \
                (char*)Vt + rr*4096 + wbase); } }
// beta: buf[q][g] = beta[nb+q][(MB) + (g^(q&7))*4 .. +4)  (128 q x 8 granules)
#define STAGEB(BUF, MB) { \
  _Pragma("unroll") \
  for (int rr=0; rr<4; rr++){ \
    const int o_ = rr*4096 + tid*16; \
    const int row_ = o_ >> 7; \
    const int g_ = (o_ >> 4) & 7; \
    gload_lds16(betab + (size_t)(nb+row_)*N_ + (MB) + ((g_ ^ (row_&7))<<2), \
                (char*)Bl + (BUF)*16384 + rr*4096 + wbase); } }

  // prologue: K(0), V-pair(0,1), beta(0)
  STAGEK(mh*512)
  STAGEV(mh*512)
  STAGEB(0, mh*512)
  __syncthreads();

  for (int mt = 0; mt < 16; mt++){
    const int mb = mh*512 + mt*32;
    // issue NEXT tile's beta (flies under this tile's compute)
    if (mt + 1 < 16){
      STAGEB((mt+1)&1, mb+32)
    }
    // beta(mt) from LDS
    const float* Bp = Bl + (mt&1)*4096;
    f32x4 bv[4];
    #pragma unroll
    for (int j=0;j<4;j++)
      bv[j] = *(const f32x4*)&Bp[(32*w + q31)*32 + (((2*j+hi) ^ (q31&7))<<2)];
    // S^T = K . Q
    f32x16 sacc;
    #pragma unroll
    for (int e=0;e<16;e++) sacc[e] = 0.f;
    __builtin_amdgcn_s_setprio(1);
    #pragma unroll
    for (int ks=0; ks<16; ks++){
      const s16x8 kf = *(const s16x8*)
          &Klds[q31*256 + (((2*ks + hi) ^ q31) << 3)];
      sacc = __builtin_amdgcn_mfma_f32_32x32x16_bf16(kf, qf[ks], sacc, 0, 0, 0);
    }
    __builtin_amdgcn_s_setprio(0);
    // P = exp(S*beta)
    float p[16];
    #pragma unroll
    for (int r=0;r<16;r++){
      p[r] = __expf(sacc[r] * bv[r>>2][r&3]);
      psum += p[r];
    }
    // PA A-frags via cross-half exchange, then PV (V half selected by mt&1)
    __builtin_amdgcn_s_setprio(1);
    #pragma unroll
    for (int u=0; u<2; u++){
      unsigned X  = ((unsigned)f2bf(p[8*u+1])<<16) | f2bf(p[8*u+0]);
      unsigned X2 = ((unsigned)f2bf(p[8*u+3])<<16) | f2bf(p[8*u+2]);
      unsigned Y  = ((unsigned)f2bf(p[8*u+5])<<16) | f2bf(p[8*u+4]);
      unsigned Y2 = ((unsigned)f2bf(p[8*u+7])<<16) | f2bf(p[8*u+6]);
      unsigned Xs  = (unsigned)__shfl_xor((int)X,  32, 64);
      unsigned X2s = (unsigned)__shfl_xor((int)X2, 32, 64);
      unsigned Ys  = (unsigned)__shfl_xor((int)Y,  32, 64);
      unsigned Y2s = (unsigned)__shfl_xor((int)Y2, 32, 64);
      union { unsigned uu[4]; s16x8 v; } pa;
      pa.uu[0] = hi ? Ys  : X;
      pa.uu[1] = hi ? Y2s : X2;
      pa.uu[2] = hi ? Y   : Xs;
      pa.uu[3] = hi ? Y2  : X2s;
      const int s = 2*(mt&1) + u;
      #pragma unroll
      for (int ct=0; ct<8; ct++){
        const int c = 32*ct + q31;
        const s16x8 vf = *(const s16x8*)
            &Vt[c*64 + (((2*s + hi) ^ (c&7)) << 3)];
        oacc[ct] = __builtin_amdgcn_mfma_f32_32x32x16_bf16(pa.v, vf, oacc[ct], 0,0,0);
      }
    }
    __builtin_amdgcn_s_setprio(0);
    // barrier A: LDS reads of tile mt done (VMEM queue untouched)
    asm volatile("s_waitcnt lgkmcnt(0)" ::: "memory");
    __builtin_amdgcn_s_barrier();
    // stage next K (every tile) and next V-pair (every other tile)
    if (mt + 1 < 16){
      STAGEK(mb + 32)
      if (((mt + 1) & 1) == 0){
        STAGEV(mh*512 + (mt + 1)*32)
      }
    }
    __syncthreads();   // drains K/V staging + the already-flown beta(t+1)
  }
#undef STAGEK
#undef STAGEV
#undef STAGEB

  psum += __shfl_xor(psum, 32, 64);
  unsigned short* Ob = Opb + ((size_t)mh*8 + b)*(size_t)N_*C_;
  #pragma unroll
  for (int ct=0; ct<8; ct++){
    const int c = 32*ct + q31;
    #pragma unroll
    for (int r=0;r<16;r++){
      const int qo = nb + 32*w + (r&3) + 8*(r>>2) + 4*hi;
      Ob[(size_t)qo*C_ + c] = f2bf(oacc[ct][r]);
    }
  }
  if (hi == 0){
    float* Lb = Ls + ((size_t)mh*8 + b)*N_;
    Lb[qr] = psum;
  }
}

// ---------------- fused MLP: merge+normalize -> conv1(BN,ReLU) -> conv2(BN,ReLU)
// -> conv3(+bias) -> residual add, all through LDS (overlaid phases).
__global__ __launch_bounds__(256) void k_mlpf(
    const unsigned short* __restrict__ Opb, const float* __restrict__ Ls,
    const unsigned short* __restrict__ W1, const float* __restrict__ sc1,
    const float* __restrict__ sh1,
    const unsigned short* __restrict__ W2, const float* __restrict__ sc2,
    const float* __restrict__ sh2,
    const unsigned short* __restrict__ W3, const float* __restrict__ b3,
    const float* __restrict__ x, float* __restrict__ out)
{
  __shared__ __align__(16) char smem[65792];
  unsigned short* Alds = (unsigned short*)smem;            // [64][256] @0 (phase1)
  unsigned short* H2   = (unsigned short*)(smem + 33024);  // [64][128]
  unsigned short* H1   = (unsigned short*)(smem + 49408);  // [64][128]
  float*          Dlds = (float*)smem;                     // [64][129] (phase3)
  int b = blockIdx.y, nt = blockIdx.x, nb = nt*64;
  int tid = threadIdx.x;
  const size_t PS = (size_t)8*N_*C_;
  for (int i = tid; i < 64*32; i += 256){
    int r = i >> 5, cv = i & 31;
    int row = nb + r;
    float ls = Ls[(size_t)b*N_ + row] + Ls[(size_t)(8+b)*N_ + row]
             + Ls[(size_t)(16+b)*N_ + row] + Ls[(size_t)(24+b)*N_ + row];
    float inv = 1.f / ls;
    size_t base = ((size_t)b*N_ + row)*C_ + cv*8;
    float a8[8] = {0.f,0.f,0.f,0.f,0.f,0.f,0.f,0.f};
    #pragma unroll
    for (int m=0;m<4;m++){
      s16x8 v = *(const s16x8*)&Opb[(size_t)m*PS + base];
      #pragma unroll
      for (int j=0;j<8;j++) a8[j] += bf2f((unsigned short)v[j]);
    }
    s16x8 o;
    #pragma unroll
    for (int j=0;j<8;j++) o[j] = (short)f2bf(a8[j] * inv);
    *(s16x8*)&Alds[r*256 + ((cv*8) ^ ((r&7)<<3))] = o;
  }
  __syncthreads();
  int w = tid >> 6, l = tid & 63, lr = l & 15, lq = l >> 4;
  f32x4 zero = {0.f,0.f,0.f,0.f};
  {
    f32x4 acc[8];
    #pragma unroll
    for (int i=0;i<8;i++) acc[i] = zero;
    #pragma unroll
    for (int ks = 0; ks < 8; ks++){
      s16x8 a = *(const s16x8*)&Alds[(16*w + lr)*256 + ((32*ks + 8*lq) ^ ((lr&7)<<3))];
      #pragma unroll
      for (int ct = 0; ct < 8; ct++){
        s16x8 bw = *(const s16x8*)&W1[(size_t)(16*ct + lr)*C_ + 32*ks + 8*lq];
        acc[ct] = __builtin_amdgcn_mfma_f32_16x16x32_bf16(a, bw, acc[ct], 0, 0, 0);
      }
    }
    __syncthreads();
    #pragma unroll
    for (int ct = 0; ct < 8; ct++){
      int o = 16*ct + lr;
      float s_ = sc1[o], h_ = sh1[o];
      #pragma unroll
      for (int r = 0; r < 4; r++){
        int row = 16*w + 4*lq + r;
        H1[row*128 + (o ^ ((row&7)<<3))] = f2bf(fmaxf(acc[ct][r]*s_ + h_, 0.f));
      }
    }
  }
  __syncthreads();
  {
    f32x4 acc[8];
    #pragma unroll
    for (int i=0;i<8;i++) acc[i] = zero;
    #pragma unroll
    for (int ks = 0; ks < 4; ks++){
      s16x8 a = *(const s16x8*)&H1[(16*w + lr)*128 + ((32*ks + 8*lq) ^ ((lr&7)<<3))];
      #pragma unroll
      for (int ct = 0; ct < 8; ct++){
        s16x8 bw = *(const s16x8*)&W2[(size_t)(16*ct + lr)*HC + 32*ks + 8*lq];
        acc[ct] = __builtin_amdgcn_mfma_f32_16x16x32_bf16(a, bw, acc[ct], 0, 0, 0);
      }
    }
    __syncthreads();
    #pragma unroll
    for (int ct = 0; ct < 8; ct++){
      int o = 16*ct + lr;
      float s_ = sc2[o], h_ = sh2[o];
      #pragma unroll
      for (int r = 0; r < 4; r++){
        int row = 16*w + 4*lq + r;
        H2[row*128 + (o ^ ((row&7)<<3))] = f2bf(fmaxf(acc[ct][r]*s_ + h_, 0.f));
      }
    }
  }
  __syncthreads();
  f32x4 acc[16];
  #pragma unroll
  for (int i=0;i<16;i++) acc[i] = zero;
  #pragma unroll
  for (int ks = 0; ks < 4; ks++){
    s16x8 a = *(const s16x8*)&H2[(16*w + lr)*128 + ((32*ks + 8*lq) ^ ((lr&7)<<3))];
    #pragma unroll
    for (int ct = 0; ct < 16; ct++){
      s16x8 bw = *(const s16x8*)&W3[(size_t)(16*ct + lr)*HC + 32*ks + 8*lq];
      acc[ct] = __builtin_amdgcn_mfma_f32_16x16x32_bf16(a, bw, acc[ct], 0, 0, 0);
    }
  }
  const float* xb = x + (size_t)b*C_*N_;
  float* ob = out + (size_t)b*C_*N_;
  int j = tid & 63, o0 = tid >> 6;
  #pragma unroll
  for (int half = 0; half < 2; half++){
    __syncthreads();
    #pragma unroll
    for (int ct = 8*half; ct < 8*half+8; ct++){
      int o = 16*ct + lr;
      float bi = b3[o];
      #pragma unroll
      for (int r = 0; r < 4; r++){
        int row = 16*w + 4*lq + r;
        Dlds[row*129 + (o - 128*half)] = acc[ct][r] + bi;
      }
    }
    __syncthreads();
    for (int o = 128*half + o0; o < 128*half + 128; o += 4)
      ob[(size_t)o*N_ + nb + j] = xb[(size_t)o*N_ + nb + j]
                                + Dlds[j*129 + (o - 128*half)];
  }
}

extern "C" void kernel_launch(void* const* d_in, const int* in_sizes, int n_in,
                              void* d_out, int out_size, void* d_ws, size_t ws_size,
                              hipStream_t stream)
{
  const float* x    = (const float*)d_in[0];
  const float* beta = (const float*)d_in[1];
  const float* wq = (const float*)d_in[2];  const float* bq = (const float*)d_in[3];
  const float* wk = (const float*)d_in[4];  const float* bk = (const float*)d_in[5];
  const float* wv = (const float*)d_in[6];  const float* bv = (const float*)d_in[7];
  const float* w1 = (const float*)d_in[8];  const float* b1 = (const float*)d_in[9];
  const float* g1 = (const float*)d_in[10]; const float* be1= (const float*)d_in[11];
  const float* m1 = (const float*)d_in[12]; const float* v1 = (const float*)d_in[13];
  const float* w2 = (const float*)d_in[14]; const float* b2 = (const float*)d_in[15];
  const float* g2 = (const float*)d_in[16]; const float* be2= (const float*)d_in[17];
  const float* m2 = (const float*)d_in[18]; const float* v2 = (const float*)d_in[19];
  const float* w3 = (const float*)d_in[20]; const float* b3 = (const float*)d_in[21];

  char* p = (char*)d_ws;
  auto alloc = [&](size_t n){ char* r = p; p += (n + 255) & ~(size_t)255; return r; };
  unsigned short* Qn  = (unsigned short*)alloc((size_t)B_*N_*C_*2);
  unsigned short* Kn  = (unsigned short*)alloc((size_t)B_*N_*C_*2);
  unsigned short* Vc  = (unsigned short*)alloc((size_t)B_*N_*C_*2);
  unsigned short* Opb = (unsigned short*)alloc((size_t)4*B_*N_*C_*2);
  float* Ls = (float*)alloc((size_t)4*B_*N_*4);
  unsigned short* wqb = (unsigned short*)alloc(65536*2);
  unsigned short* wkb = (unsigned short*)alloc(65536*2);
  unsigned short* wvb = (unsigned short*)alloc(65536*2);
  unsigned short* w1b = (unsigned short*)alloc(32768*2);
  unsigned short* w2b = (unsigned short*)alloc(16384*2);
  unsigned short* w3b = (unsigned short*)alloc(32768*2);
  float* sc1 = (float*)alloc(128*4);
  float* sh1 = (float*)alloc(128*4);
  float* sc2 = (float*)alloc(128*4);
  float* sh2 = (float*)alloc(128*4);

  PrepArgs pa;
  pa.s0 = wq; pa.s1 = wk; pa.s2 = wv; pa.s3 = w1; pa.s4 = w2; pa.s5 = w3;
  pa.d0 = wqb; pa.d1 = wkb; pa.d2 = wvb; pa.d3 = w1b; pa.d4 = w2b; pa.d5 = w3b;
  pa.b1 = b1; pa.g1 = g1; pa.be1 = be1; pa.m1 = m1; pa.v1 = v1;
  pa.b2 = b2; pa.g2 = g2; pa.be2 = be2; pa.m2 = m2; pa.v2 = v2;
  pa.sc1 = sc1; pa.sh1 = sh1; pa.sc2 = sc2; pa.sh2 = sh2;

  k_prep<<<dim3(1089), dim3(256), 0, stream>>>(pa);
  k_qkv<<<dim3(32, 8), dim3(256), 0, stream>>>(x, wqb, wkb, wvb, bq, bk, bv, Qn, Kn, Vc);
  k_attn<<<dim3(512), dim3(256), 0, stream>>>(Qn, Kn, Vc, beta, Opb, Ls);
  k_mlpf<<<dim3(32, 8), dim3(256), 0, stream>>>(Opb, Ls, w1b, sc1, sh1,
                                                w2b, sc2, sh2, w3b, b3,
                                                x, (float*)d_out);
}

// Round 14
// 172.558 us; speedup vs baseline: 1.1872x; 1.0615x over previous
//
#include <hip/hip_runtime.h>
#include <stdint.h>

#define B_ 8
#define C_ 256
#define N_ 2048
#define HC 128

typedef float f32x4 __attribute__((ext_vector_type(4)));
typedef short s16x8 __attribute__((ext_vector_type(8)));

__device__ __forceinline__ unsigned short f2bf(float f){
  union { float f; unsigned u; } v; v.f = f;
  unsigned r = v.u + 0x7FFF + ((v.u >> 16) & 1u);
  return (unsigned short)(r >> 16);
}
__device__ __forceinline__ float bf2f(unsigned short u){
  union { unsigned u; float f; } v; v.u = ((unsigned)u) << 16;
  return v.f;
}
__device__ __forceinline__ void gload_lds16(const void* g, void* l){
  __builtin_amdgcn_global_load_lds(
      (const __attribute__((address_space(1))) unsigned int*)g,
      (__attribute__((address_space(3))) unsigned int*)l, 16, 0, 0);
}

// ---------------- prep: weights -> bf16, BN affine fold ----------------
struct PrepArgs {
  const float *s0,*s1,*s2,*s3,*s4,*s5;
  unsigned short *d0,*d1,*d2,*d3,*d4,*d5;
  const float *b1,*g1,*be1,*m1,*v1;
  const float *b2,*g2,*be2,*m2,*v2;
  float *sc1,*sh1,*sc2,*sh2;
};

__global__ __launch_bounds__(256) void k_prep(PrepArgs a){
  int gid = blockIdx.x*256 + threadIdx.x;
  const int S0=65536, S1=131072, S2=196608, S3=229376, S4=245760, S5=278528;
  if (gid < S0)      a.d0[gid]    = f2bf(a.s0[gid]);
  else if (gid < S1) a.d1[gid-S0] = f2bf(a.s1[gid-S0]);
  else if (gid < S2) a.d2[gid-S1] = f2bf(a.s2[gid-S1]);
  else if (gid < S3) a.d3[gid-S2] = f2bf(a.s3[gid-S2]);
  else if (gid < S4) a.d4[gid-S3] = f2bf(a.s4[gid-S3]);
  else if (gid < S5) a.d5[gid-S4] = f2bf(a.s5[gid-S4]);
  else if (gid < S5+128){
    int o = gid - S5;
    float inv = a.g1[o] * rsqrtf(a.v1[o] + 1e-5f);
    a.sc1[o] = inv;
    a.sh1[o] = a.b1[o]*inv + a.be1[o] - a.m1[o]*inv;
  } else if (gid < S5+256){
    int o = gid - S5 - 128;
    float inv = a.g2[o] * rsqrtf(a.v2[o] + 1e-5f);
    a.sc2[o] = inv;
    a.sh2[o] = a.b2[o]*inv + a.be2[o] - a.m2[o]*inv;
  }
}

// ---------------- fused: x-transpose + QKV GEMM (z-split for parallelism) ----
__global__ __launch_bounds__(256) void k_qkv(
    const float* __restrict__ x,
    const unsigned short* __restrict__ wqb, const unsigned short* __restrict__ wkb,
    const unsigned short* __restrict__ wvb,
    const float* __restrict__ bq, const float* __restrict__ bk, const float* __restrict__ bv,
    unsigned short* __restrict__ Qn, unsigned short* __restrict__ Kn,
    unsigned short* __restrict__ Vc)
{
  __shared__ unsigned short Alds[64][256];
  __shared__ unsigned short Tlds[64][260];
  int b = blockIdx.y, nt = blockIdx.x, z = blockIdx.z;
  int nb = nt*64;
  const float* xb = x + (size_t)b*C_*N_;
  int tid = threadIdx.x;
  float* Tf = (float*)&Tlds[0][0];   // [64][65]
  int tn = tid & 63, tq = tid >> 6;
  for (int c0 = 0; c0 < 256; c0 += 64){
    #pragma unroll
    for (int cc = tq; cc < 64; cc += 4)
      Tf[tn*65 + cc] = xb[(size_t)(c0+cc)*N_ + nb + tn];
    __syncthreads();
    #pragma unroll
    for (int nl = tq; nl < 64; nl += 4){
      int c = c0 + tn;
      Alds[nl][c ^ ((nl&7)<<3)] = f2bf(Tf[nl*65 + tn]);
    }
    __syncthreads();
  }
  int w = tid >> 6, l = tid & 63, lr = l & 15, lq = l >> 4;
  const unsigned short* W = (z==0) ? wqb : (z==1 ? wkb : wvb);
  const float* bias = (z==0) ? bq : (z==1 ? bk : bv);
  f32x4 zero = {0.f,0.f,0.f,0.f};
  f32x4 acc[16];
  #pragma unroll
  for (int i=0;i<16;i++) acc[i] = zero;
  #pragma unroll
  for (int ks = 0; ks < 8; ks++){
    s16x8 a = *(const s16x8*)&Alds[16*w + lr][(32*ks + 8*lq) ^ ((lr&7)<<3)];
    #pragma unroll
    for (int ct = 0; ct < 16; ct++){
      s16x8 bw = *(const s16x8*)&W[(size_t)(16*ct + lr)*C_ + 32*ks + 8*lq];
      acc[ct] = __builtin_amdgcn_mfma_f32_16x16x32_bf16(a, bw, acc[ct], 0, 0, 0);
    }
  }
  if (z < 2){
    unsigned short* ob = (z==0 ? Qn : Kn) + ((size_t)b*N_ + nb)*C_;
    #pragma unroll
    for (int ct = 0; ct < 16; ct++){
      int o = 16*ct + lr;
      float bi = bias[o];
      #pragma unroll
      for (int r = 0; r < 4; r++){
        int row = 16*w + 4*lq + r;
        ob[(size_t)row*C_ + o] = f2bf(acc[ct][r] + bi);
      }
    }
  } else {
    __syncthreads();
    #pragma unroll
    for (int ct = 0; ct < 16; ct++){
      int o = 16*ct + lr;
      float bi = bias[o];
      #pragma unroll
      for (int r = 0; r < 4; r++)
        Tlds[16*w + 4*lq + r][o] = f2bf(acc[ct][r] + bi);
    }
    __syncthreads();
    unsigned short* vb = Vc + (size_t)b*C_*N_;
    int j = tid & 63, o0 = tid >> 6;
    #pragma unroll
    for (int o = o0; o < 256; o += 4)
      vb[(size_t)o*N_ + nb + j] = Tlds[j][o];
  }
}

// ---------------- attention: 16x16 frags, q-tile 64, 12 waves/CU ----------------
// grid 1024 x 256 thr = 3 blocks/CU (53KB LDS, launch_bounds(256,3)).
// 1.5x more streaming waves than R12 (per-wave HBM stream rate is the binding
// constant). KVBLK=32, m-split 4. Plain NT fragment maps (k_gemm-verified).
// No-max softmax; P->PV via per-wave Plds. R10's beta-dbuf pipeline.
// R13 bug fixed: beta LDS read now includes the wave's q-row offset 16*w.
__global__ __launch_bounds__(256, 3) void k_attn(
    const unsigned short* __restrict__ Qn, const unsigned short* __restrict__ Kn,
    const unsigned short* __restrict__ Vc, const float* __restrict__ beta,
    unsigned short* __restrict__ Opb, float* __restrict__ Ls)
{
  __shared__ __align__(16) char smem[54528];
  unsigned short* Klds = (unsigned short*)smem;             // 16 KB [32 m][256 c]
  unsigned short* Vt   = (unsigned short*)(smem + 16384);   // 16 KB [256 c][32 m]
  float*          Bl   = (float*)(smem + 32768);            // 2x8KB [64 q][32 m]
  unsigned short* Pl   = (unsigned short*)(smem + 49152);   // 4x[16][40] bf16
  const int tid = threadIdx.x;
  const int bid = blockIdx.x;
  const int b = bid & 7;
  const int jj = bid >> 3;                 // 0..127
  const int nt = jj & 31, mh = jj >> 5;    // nt 0..31, mh 0..3
  const int nb = nt*64;
  const unsigned short* Qb = Qn + (size_t)b*N_*C_;
  const unsigned short* Kb = Kn + (size_t)b*N_*C_;
  const unsigned short* Vb = Vc + (size_t)b*C_*N_;
  const float* betab = beta + (size_t)b*N_*N_;
  const int w = tid >> 6, lane = tid & 63, lr = lane & 15, lq = lane >> 4;
  const int wbase = (tid & ~63) * 16;
  unsigned short* Pw = Pl + w*16*40;

  // Q A-frags: qf[ks] = Q[nb+16w+lr][32ks+8lq .. +8]  (regs whole kernel)
  s16x8 qf[8];
  {
    const unsigned short* qp = Qb + (size_t)(nb + 16*w + lr)*C_ + 8*lq;
    #pragma unroll
    for (int ks = 0; ks < 8; ks++)
      qf[ks] = *(const s16x8*)&qp[32*ks];
  }
  f32x4 zero = {0.f,0.f,0.f,0.f};
  f32x4 oacc[16];
  #pragma unroll
  for (int i=0;i<16;i++) oacc[i] = zero;
  float psum[4] = {0.f,0.f,0.f,0.f};

// K: LDS[row][slot16B] = K[mb+row][(slot^(row&31))*8 .. +8)  (32 rows x 32 slots)
#define STAGEK(MB) { \
  _Pragma("unroll") \
  for (int rr=0; rr<4; rr++){ \
    const int o_ = rr*4096 + tid*16; \
    const int row_ = o_ >> 9; \
    const int slot_ = (o_ >> 4) & 31; \
    gload_lds16(Kb + (size_t)((MB)+row_)*C_ + ((slot_ ^ (row_&31))<<3), \
                (char*)Klds + rr*4096 + wbase); } }
// V: LDS[c][slot16B] = V[c][(MB) + (slot^(c&3))*8 .. +8)   (256 c x 4 slots)
#define STAGEV(MB) { \
  _Pragma("unroll") \
  for (int rr=0; rr<4; rr++){ \
    const int o_ = rr*4096 + tid*16; \
    const int c_ = o_ >> 6; \
    const int slot_ = (o_ >> 4) & 3; \
    gload_lds16(Vb + (size_t)c_*N_ + (MB) + ((slot_ ^ (c_&3))<<3), \
                (char*)Vt + rr*4096 + wbase); } }
// beta: buf[q][m] f32 linear   (64 q x 32 m = 8KB, 2 loads/thread)
#define STAGEB(BUF, MB) { \
  _Pragma("unroll") \
  for (int rr=0; rr<2; rr++){ \
    const int o_ = rr*4096 + tid*16; \
    const int row_ = o_ >> 7; \
    const int g_ = (o_ >> 4) & 7; \
    gload_lds16(betab + (size_t)(nb+row_)*N_ + (MB) + g_*4, \
                (char*)Bl + (BUF)*8192 + rr*4096 + wbase); } }

  // prologue: K(0), V(0), beta(0)
  STAGEK(mh*512)
  STAGEV(mh*512)
  STAGEB(0, mh*512)
  __syncthreads();

  for (int mt = 0; mt < 16; mt++){
    const int mb = mh*512 + mt*32;
    // issue NEXT tile's beta (flies under this tile's compute)
    if (mt + 1 < 16){
      STAGEB((mt+1)&1, mb+32)
    }
    const float* Bp = Bl + (mt&1)*2048;
    // S = Q K^T : S[q=16w+4lq+r][m=16ct+lr]
    f32x4 sacc[2];
    sacc[0] = zero; sacc[1] = zero;
    __builtin_amdgcn_s_setprio(1);
    #pragma unroll
    for (int ks=0; ks<8; ks++){
      #pragma unroll
      for (int ct=0; ct<2; ct++){
        const int row = 16*ct + lr;
        const s16x8 kf = *(const s16x8*)
            &Klds[row*256 + (((4*ks + lq) ^ (row&31)) << 3)];
        sacc[ct] = __builtin_amdgcn_mfma_f32_16x16x32_bf16(qf[ks], kf, sacc[ct], 0,0,0);
      }
    }
    __builtin_amdgcn_s_setprio(0);
    // P = exp(S*beta); psum partial; pack to per-wave Plds
    #pragma unroll
    for (int ct=0; ct<2; ct++)
      #pragma unroll
      for (int r=0; r<4; r++){
        float be = Bp[(16*w + 4*lq + r)*32 + 16*ct + lr];
        float p = __expf(sacc[ct][r] * be);
        psum[r] += p;
        Pw[(4*lq + r)*40 + 16*ct + lr] = f2bf(p);
      }
    // PV: O[q][c] += P[q][m] V[c][m]   (K=32, one MFMA per ct)
    {
      const s16x8 pf = *(const s16x8*)&Pw[lr*40 + 8*lq];
      __builtin_amdgcn_s_setprio(1);
      #pragma unroll
      for (int ct=0; ct<16; ct++){
        const int c = 16*ct + lr;
        const s16x8 vf = *(const s16x8*)
            &Vt[c*32 + ((lq ^ (c&3)) << 3)];
        oacc[ct] = __builtin_amdgcn_mfma_f32_16x16x32_bf16(pf, vf, oacc[ct], 0,0,0);
      }
      __builtin_amdgcn_s_setprio(0);
    }
    // barrier A: LDS reads done (VMEM queue untouched)
    asm volatile("s_waitcnt lgkmcnt(0)" ::: "memory");
    __builtin_amdgcn_s_barrier();
    if (mt + 1 < 16){
      STAGEK(mb + 32)
      STAGEV(mb + 32)
    }
    __syncthreads();   // drains K/V staging + already-flown beta(t+1)
  }
#undef STAGEK
#undef STAGEV
#undef STAGEB

  // psum reduce over the 16-lane lr group (lanes share (w,lq) -> same q rows)
  #pragma unroll
  for (int r=0;r<4;r++){
    #pragma unroll
    for (int d=1; d<16; d<<=1) psum[r] += __shfl_xor(psum[r], d, 64);
  }
  // store unnormalized bf16 partials
  unsigned short* Ob = Opb + ((size_t)mh*8 + b)*(size_t)N_*C_;
  #pragma unroll
  for (int ct=0; ct<16; ct++){
    const int c = 16*ct + lr;
    #pragma unroll
    for (int r=0; r<4; r++){
      const int qo = nb + 16*w + 4*lq + r;
      Ob[(size_t)qo*C_ + c] = f2bf(oacc[ct][r]);
    }
  }
  if (lr == 0){
    float* Lb = Ls + ((size_t)mh*8 + b)*N_;
    #pragma unroll
    for (int r=0;r<4;r++) Lb[nb + 16*w + 4*lq + r] = psum[r];
  }
}

// ---------------- fused MLP: merge+normalize -> conv1(BN,ReLU) -> conv2(BN,ReLU)
// -> conv3(+bias) -> residual add, all through LDS (overlaid phases).
__global__ __launch_bounds__(256) void k_mlpf(
    const unsigned short* __restrict__ Opb, const float* __restrict__ Ls,
    const unsigned short* __restrict__ W1, const float* __restrict__ sc1,
    const float* __restrict__ sh1,
    const unsigned short* __restrict__ W2, const float* __restrict__ sc2,
    const float* __restrict__ sh2,
    const unsigned short* __restrict__ W3, const float* __restrict__ b3,
    const float* __restrict__ x, float* __restrict__ out)
{
  __shared__ __align__(16) char smem[65792];
  unsigned short* Alds = (unsigned short*)smem;            // [64][256] @0 (phase1)
  unsigned short* H2   = (unsigned short*)(smem + 33024);  // [64][128]
  unsigned short* H1   = (unsigned short*)(smem + 49408);  // [64][128]
  float*          Dlds = (float*)smem;                     // [64][129] (phase3)
  int b = blockIdx.y, nt = blockIdx.x, nb = nt*64;
  int tid = threadIdx.x;
  const size_t PS = (size_t)8*N_*C_;
  for (int i = tid; i < 64*32; i += 256){
    int r = i >> 5, cv = i & 31;
    int row = nb + r;
    float ls = Ls[(size_t)b*N_ + row] + Ls[(size_t)(8+b)*N_ + row]
             + Ls[(size_t)(16+b)*N_ + row] + Ls[(size_t)(24+b)*N_ + row];
    float inv = 1.f / ls;
    size_t base = ((size_t)b*N_ + row)*C_ + cv*8;
    float a8[8] = {0.f,0.f,0.f,0.f,0.f,0.f,0.f,0.f};
    #pragma unroll
    for (int m=0;m<4;m++){
      s16x8 v = *(const s16x8*)&Opb[(size_t)m*PS + base];
      #pragma unroll
      for (int j=0;j<8;j++) a8[j] += bf2f((unsigned short)v[j]);
    }
    s16x8 o;
    #pragma unroll
    for (int j=0;j<8;j++) o[j] = (short)f2bf(a8[j] * inv);
    *(s16x8*)&Alds[r*256 + ((cv*8) ^ ((r&7)<<3))] = o;
  }
  __syncthreads();
  int w = tid >> 6, l = tid & 63, lr = l & 15, lq = l >> 4;
  f32x4 zero = {0.f,0.f,0.f,0.f};
  {
    f32x4 acc[8];
    #pragma unroll
    for (int i=0;i<8;i++) acc[i] = zero;
    #pragma unroll
    for (int ks = 0; ks < 8; ks++){
      s16x8 a = *(const s16x8*)&Alds[(16*w + lr)*256 + ((32*ks + 8*lq) ^ ((lr&7)<<3))];
      #pragma unroll
      for (int ct = 0; ct < 8; ct++){
        s16x8 bw = *(const s16x8*)&W1[(size_t)(16*ct + lr)*C_ + 32*ks + 8*lq];
        acc[ct] = __builtin_amdgcn_mfma_f32_16x16x32_bf16(a, bw, acc[ct], 0, 0, 0);
      }
    }
    __syncthreads();
    #pragma unroll
    for (int ct = 0; ct < 8; ct++){
      int o = 16*ct + lr;
      float s_ = sc1[o], h_ = sh1[o];
      #pragma unroll
      for (int r = 0; r < 4; r++){
        int row = 16*w + 4*lq + r;
        H1[row*128 + (o ^ ((row&7)<<3))] = f2bf(fmaxf(acc[ct][r]*s_ + h_, 0.f));
      }
    }
  }
  __syncthreads();
  {
    f32x4 acc[8];
    #pragma unroll
    for (int i=0;i<8;i++) acc[i] = zero;
    #pragma unroll
    for (int ks = 0; ks < 4; ks++){
      s16x8 a = *(const s16x8*)&H1[(16*w + lr)*128 + ((32*ks + 8*lq) ^ ((lr&7)<<3))];
      #pragma unroll
      for (int ct = 0; ct < 8; ct++){
        s16x8 bw = *(const s16x8*)&W2[(size_t)(16*ct + lr)*HC + 32*ks + 8*lq];
        acc[ct] = __builtin_amdgcn_mfma_f32_16x16x32_bf16(a, bw, acc[ct], 0, 0, 0);
      }
    }
    __syncthreads();
    #pragma unroll
    for (int ct = 0; ct < 8; ct++){
      int o = 16*ct + lr;
      float s_ = sc2[o], h_ = sh2[o];
      #pragma unroll
      for (int r = 0; r < 4; r++){
        int row = 16*w + 4*lq + r;
        H2[row*128 + (o ^ ((row&7)<<3))] = f2bf(fmaxf(acc[ct][r]*s_ + h_, 0.f));
      }
    }
  }
  __syncthreads();
  f32x4 acc[16];
  #pragma unroll
  for (int i=0;i<16;i++) acc[i] = zero;
  #pragma unroll
  for (int ks = 0; ks < 4; ks++){
    s16x8 a = *(const s16x8*)&H2[(16*w + lr)*128 + ((32*ks + 8*lq) ^ ((lr&7)<<3))];
    #pragma unroll
    for (int ct = 0; ct < 16; ct++){
      s16x8 bw = *(const s16x8*)&W3[(size_t)(16*ct + lr)*HC + 32*ks + 8*lq];
      acc[ct] = __builtin_amdgcn_mfma_f32_16x16x32_bf16(a, bw, acc[ct], 0, 0, 0);
    }
  }
  const float* xb = x + (size_t)b*C_*N_;
  float* ob = out + (size_t)b*C_*N_;
  int j = tid & 63, o0 = tid >> 6;
  #pragma unroll
  for (int half = 0; half < 2; half++){
    __syncthreads();
    #pragma unroll
    for (int ct = 8*half; ct < 8*half+8; ct++){
      int o = 16*ct + lr;
      float bi = b3[o];
      #pragma unroll
      for (int r = 0; r < 4; r++){
        int row = 16*w + 4*lq + r;
        Dlds[row*129 + (o - 128*half)] = acc[ct][r] + bi;
      }
    }
    __syncthreads();
    for (int o = 128*half + o0; o < 128*half + 128; o += 4)
      ob[(size_t)o*N_ + nb + j] = xb[(size_t)o*N_ + nb + j]
                                + Dlds[j*129 + (o - 128*half)];
  }
}

extern "C" void kernel_launch(void* const* d_in, const int* in_sizes, int n_in,
                              void* d_out, int out_size, void* d_ws, size_t ws_size,
                              hipStream_t stream)
{
  const float* x    = (const float*)d_in[0];
  const float* beta = (const float*)d_in[1];
  const float* wq = (const float*)d_in[2];  const float* bq = (const float*)d_in[3];
  const float* wk = (const float*)d_in[4];  const float* bk = (const float*)d_in[5];
  const float* wv = (const float*)d_in[6];  const float* bv = (const float*)d_in[7];
  const float* w1 = (const float*)d_in[8];  const float* b1 = (const float*)d_in[9];
  const float* g1 = (const float*)d_in[10]; const float* be1= (const float*)d_in[11];
  const float* m1 = (const float*)d_in[12]; const float* v1 = (const float*)d_in[13];
  const float* w2 = (const float*)d_in[14]; const float* b2 = (const float*)d_in[15];
  const float* g2 = (const float*)d_in[16]; const float* be2= (const float*)d_in[17];
  const float* m2 = (const float*)d_in[18]; const float* v2 = (const float*)d_in[19];
  const float* w3 = (const float*)d_in[20]; const float* b3 = (const float*)d_in[21];

  char* p = (char*)d_ws;
  auto alloc = [&](size_t n){ char* r = p; p += (n + 255) & ~(size_t)255; return r; };
  unsigned short* Qn  = (unsigned short*)alloc((size_t)B_*N_*C_*2);
  unsigned short* Kn  = (unsigned short*)alloc((size_t)B_*N_*C_*2);
  unsigned short* Vc  = (unsigned short*)alloc((size_t)B_*N_*C_*2);
  unsigned short* Opb = (unsigned short*)alloc((size_t)4*B_*N_*C_*2);
  float* Ls = (float*)alloc((size_t)4*B_*N_*4);
  unsigned short* wqb = (unsigned short*)alloc(65536*2);
  unsigned short* wkb = (unsigned short*)alloc(65536*2);
  unsigned short* wvb = (unsigned short*)alloc(65536*2);
  unsigned short* w1b = (unsigned short*)alloc(32768*2);
  unsigned short* w2b = (unsigned short*)alloc(16384*2);
  unsigned short* w3b = (unsigned short*)alloc(32768*2);
  float* sc1 = (float*)alloc(128*4);
  float* sh1 = (float*)alloc(128*4);
  float* sc2 = (float*)alloc(128*4);
  float* sh2 = (float*)alloc(128*4);

  PrepArgs pa;
  pa.s0 = wq; pa.s1 = wk; pa.s2 = wv; pa.s3 = w1; pa.s4 = w2; pa.s5 = w3;
  pa.d0 = wqb; pa.d1 = wkb; pa.d2 = wvb; pa.d3 = w1b; pa.d4 = w2b; pa.d5 = w3b;
  pa.b1 = b1; pa.g1 = g1; pa.be1 = be1; pa.m1 = m1; pa.v1 = v1;
  pa.b2 = b2; pa.g2 = g2; pa.be2 = be2; pa.m2 = m2; pa.v2 = v2;
  pa.sc1 = sc1; pa.sh1 = sh1; pa.sc2 = sc2; pa.sh2 = sh2;

  k_prep<<<dim3(1089), dim3(256), 0, stream>>>(pa);
  k_qkv<<<dim3(32, 8, 3), dim3(256), 0, stream>>>(x, wqb, wkb, wvb, bq, bk, bv, Qn, Kn, Vc);
  k_attn<<<dim3(1024), dim3(256), 0, stream>>>(Qn, Kn, Vc, beta, Opb, Ls);
  k_mlpf<<<dim3(32, 8), dim3(256), 0, stream>>>(Opb, Ls, w1b, sc1, sh1,
                                                w2b, sc2, sh2, w3b, b3,
                                                x, (float*)d_out);
}

// Round 15
// 172.246 us; speedup vs baseline: 1.1893x; 1.0018x over previous
//
#include <hip/hip_runtime.h>
#include <stdint.h>

#define B_ 8
#define C_ 256
#define N_ 2048
#define HC 128

typedef float f32x4 __attribute__((ext_vector_type(4)));
typedef short s16x8 __attribute__((ext_vector_type(8)));

__device__ __forceinline__ unsigned short f2bf(float f){
  union { float f; unsigned u; } v; v.f = f;
  unsigned r = v.u + 0x7FFF + ((v.u >> 16) & 1u);
  return (unsigned short)(r >> 16);
}
__device__ __forceinline__ float bf2f(unsigned short u){
  union { unsigned u; float f; } v; v.u = ((unsigned)u) << 16;
  return v.f;
}
__device__ __forceinline__ void gload_lds16(const void* g, void* l){
  __builtin_amdgcn_global_load_lds(
      (const __attribute__((address_space(1))) unsigned int*)g,
      (__attribute__((address_space(3))) unsigned int*)l, 16, 0, 0);
}

// ---------------- prep: weights -> bf16, BN affine fold ----------------
struct PrepArgs {
  const float *s0,*s1,*s2,*s3,*s4,*s5;
  unsigned short *d0,*d1,*d2,*d3,*d4,*d5;
  const float *b1,*g1,*be1,*m1,*v1;
  const float *b2,*g2,*be2,*m2,*v2;
  float *sc1,*sh1,*sc2,*sh2;
};

__global__ __launch_bounds__(256) void k_prep(PrepArgs a){
  int gid = blockIdx.x*256 + threadIdx.x;
  const int S0=65536, S1=131072, S2=196608, S3=229376, S4=245760, S5=278528;
  if (gid < S0)      a.d0[gid]    = f2bf(a.s0[gid]);
  else if (gid < S1) a.d1[gid-S0] = f2bf(a.s1[gid-S0]);
  else if (gid < S2) a.d2[gid-S1] = f2bf(a.s2[gid-S1]);
  else if (gid < S3) a.d3[gid-S2] = f2bf(a.s3[gid-S2]);
  else if (gid < S4) a.d4[gid-S3] = f2bf(a.s4[gid-S3]);
  else if (gid < S5) a.d5[gid-S4] = f2bf(a.s5[gid-S4]);
  else if (gid < S5+128){
    int o = gid - S5;
    float inv = a.g1[o] * rsqrtf(a.v1[o] + 1e-5f);
    a.sc1[o] = inv;
    a.sh1[o] = a.b1[o]*inv + a.be1[o] - a.m1[o]*inv;
  } else if (gid < S5+256){
    int o = gid - S5 - 128;
    float inv = a.g2[o] * rsqrtf(a.v2[o] + 1e-5f);
    a.sc2[o] = inv;
    a.sh2[o] = a.b2[o]*inv + a.be2[o] - a.m2[o]*inv;
  }
}

// ---------------- fused: x-transpose + QKV GEMM (z-split for parallelism) ----
__global__ __launch_bounds__(256) void k_qkv(
    const float* __restrict__ x,
    const unsigned short* __restrict__ wqb, const unsigned short* __restrict__ wkb,
    const unsigned short* __restrict__ wvb,
    const float* __restrict__ bq, const float* __restrict__ bk, const float* __restrict__ bv,
    unsigned short* __restrict__ Qn, unsigned short* __restrict__ Kn,
    unsigned short* __restrict__ Vc)
{
  __shared__ unsigned short Alds[64][256];
  __shared__ unsigned short Tlds[64][260];
  int b = blockIdx.y, nt = blockIdx.x, z = blockIdx.z;
  int nb = nt*64;
  const float* xb = x + (size_t)b*C_*N_;
  int tid = threadIdx.x;
  float* Tf = (float*)&Tlds[0][0];   // [64][65]
  int tn = tid & 63, tq = tid >> 6;
  for (int c0 = 0; c0 < 256; c0 += 64){
    #pragma unroll
    for (int cc = tq; cc < 64; cc += 4)
      Tf[tn*65 + cc] = xb[(size_t)(c0+cc)*N_ + nb + tn];
    __syncthreads();
    #pragma unroll
    for (int nl = tq; nl < 64; nl += 4){
      int c = c0 + tn;
      Alds[nl][c ^ ((nl&7)<<3)] = f2bf(Tf[nl*65 + tn]);
    }
    __syncthreads();
  }
  int w = tid >> 6, l = tid & 63, lr = l & 15, lq = l >> 4;
  const unsigned short* W = (z==0) ? wqb : (z==1 ? wkb : wvb);
  const float* bias = (z==0) ? bq : (z==1 ? bk : bv);
  f32x4 zero = {0.f,0.f,0.f,0.f};
  f32x4 acc[16];
  #pragma unroll
  for (int i=0;i<16;i++) acc[i] = zero;
  #pragma unroll
  for (int ks = 0; ks < 8; ks++){
    s16x8 a = *(const s16x8*)&Alds[16*w + lr][(32*ks + 8*lq) ^ ((lr&7)<<3)];
    #pragma unroll
    for (int ct = 0; ct < 16; ct++){
      s16x8 bw = *(const s16x8*)&W[(size_t)(16*ct + lr)*C_ + 32*ks + 8*lq];
      acc[ct] = __builtin_amdgcn_mfma_f32_16x16x32_bf16(a, bw, acc[ct], 0, 0, 0);
    }
  }
  if (z < 2){
    unsigned short* ob = (z==0 ? Qn : Kn) + ((size_t)b*N_ + nb)*C_;
    #pragma unroll
    for (int ct = 0; ct < 16; ct++){
      int o = 16*ct + lr;
      float bi = bias[o];
      #pragma unroll
      for (int r = 0; r < 4; r++){
        int row = 16*w + 4*lq + r;
        ob[(size_t)row*C_ + o] = f2bf(acc[ct][r] + bi);
      }
    }
  } else {
    __syncthreads();
    #pragma unroll
    for (int ct = 0; ct < 16; ct++){
      int o = 16*ct + lr;
      float bi = bias[o];
      #pragma unroll
      for (int r = 0; r < 4; r++)
        Tlds[16*w + 4*lq + r][o] = f2bf(acc[ct][r] + bi);
    }
    __syncthreads();
    unsigned short* vb = Vc + (size_t)b*C_*N_;
    int j = tid & 63, o0 = tid >> 6;
    #pragma unroll
    for (int o = o0; o < 256; o += 4)
      vb[(size_t)o*N_ + nb + j] = Tlds[j][o];
  }
}

// ---------------- attention: 16x16 frags, q-tile 64, 12 waves/CU ----------------
// grid 1024 x 256 thr. LDS usage 54272 B EXACTLY (= 106 x 512B granules) so
// 3 blocks/CU fit: 3 x 54272 = 162816 <= 163840. (R14 declared 54528 -> rounded
// to 54784 -> 3x = 164352 > 160KB, silently capping at 2 blocks/CU.)
// KVBLK=32, m-split 4, plain NT fragment maps, no-max softmax, R10 beta dbuf.
__global__ __launch_bounds__(256, 3) void k_attn(
    const unsigned short* __restrict__ Qn, const unsigned short* __restrict__ Kn,
    const unsigned short* __restrict__ Vc, const float* __restrict__ beta,
    unsigned short* __restrict__ Opb, float* __restrict__ Ls)
{
  __shared__ __align__(16) char smem[54272];
  unsigned short* Klds = (unsigned short*)smem;             // 16 KB [32 m][256 c]
  unsigned short* Vt   = (unsigned short*)(smem + 16384);   // 16 KB [256 c][32 m]
  float*          Bl   = (float*)(smem + 32768);            // 2x8KB [64 q][32 m]
  unsigned short* Pl   = (unsigned short*)(smem + 49152);   // 4x[16][40] bf16 = 5120B
  const int tid = threadIdx.x;
  const int bid = blockIdx.x;
  const int b = bid & 7;
  const int jj = bid >> 3;                 // 0..127
  const int nt = jj & 31, mh = jj >> 5;    // nt 0..31, mh 0..3
  const int nb = nt*64;
  const unsigned short* Qb = Qn + (size_t)b*N_*C_;
  const unsigned short* Kb = Kn + (size_t)b*N_*C_;
  const unsigned short* Vb = Vc + (size_t)b*C_*N_;
  const float* betab = beta + (size_t)b*N_*N_;
  const int w = tid >> 6, lane = tid & 63, lr = lane & 15, lq = lane >> 4;
  const int wbase = (tid & ~63) * 16;
  unsigned short* Pw = Pl + w*16*40;

  // Q A-frags: qf[ks] = Q[nb+16w+lr][32ks+8lq .. +8]  (regs whole kernel)
  s16x8 qf[8];
  {
    const unsigned short* qp = Qb + (size_t)(nb + 16*w + lr)*C_ + 8*lq;
    #pragma unroll
    for (int ks = 0; ks < 8; ks++)
      qf[ks] = *(const s16x8*)&qp[32*ks];
  }
  f32x4 zero = {0.f,0.f,0.f,0.f};
  f32x4 oacc[16];
  #pragma unroll
  for (int i=0;i<16;i++) oacc[i] = zero;
  float psum[4] = {0.f,0.f,0.f,0.f};

// K: LDS[row][slot16B] = K[mb+row][(slot^(row&31))*8 .. +8)  (32 rows x 32 slots)
#define STAGEK(MB) { \
  _Pragma("unroll") \
  for (int rr=0; rr<4; rr++){ \
    const int o_ = rr*4096 + tid*16; \
    const int row_ = o_ >> 9; \
    const int slot_ = (o_ >> 4) & 31; \
    gload_lds16(Kb + (size_t)((MB)+row_)*C_ + ((slot_ ^ (row_&31))<<3), \
                (char*)Klds + rr*4096 + wbase); } }
// V: LDS[c][slot16B] = V[c][(MB) + (slot^(c&3))*8 .. +8)   (256 c x 4 slots)
#define STAGEV(MB) { \
  _Pragma("unroll") \
  for (int rr=0; rr<4; rr++){ \
    const int o_ = rr*4096 + tid*16; \
    const int c_ = o_ >> 6; \
    const int slot_ = (o_ >> 4) & 3; \
    gload_lds16(Vb + (size_t)c_*N_ + (MB) + ((slot_ ^ (c_&3))<<3), \
                (char*)Vt + rr*4096 + wbase); } }
// beta: buf[q][m] f32 linear   (64 q x 32 m = 8KB, 2 loads/thread)
#define STAGEB(BUF, MB) { \
  _Pragma("unroll") \
  for (int rr=0; rr<2; rr++){ \
    const int o_ = rr*4096 + tid*16; \
    const int row_ = o_ >> 7; \
    const int g_ = (o_ >> 4) & 7; \
    gload_lds16(betab + (size_t)(nb+row_)*N_ + (MB) + g_*4, \
                (char*)Bl + (BUF)*8192 + rr*4096 + wbase); } }

  // prologue: K(0), V(0), beta(0)
  STAGEK(mh*512)
  STAGEV(mh*512)
  STAGEB(0, mh*512)
  __syncthreads();

  for (int mt = 0; mt < 16; mt++){
    const int mb = mh*512 + mt*32;
    // issue NEXT tile's beta (flies under this tile's compute)
    if (mt + 1 < 16){
      STAGEB((mt+1)&1, mb+32)
    }
    const float* Bp = Bl + (mt&1)*2048;
    // S = Q K^T : S[q=16w+4lq+r][m=16ct+lr]
    f32x4 sacc[2];
    sacc[0] = zero; sacc[1] = zero;
    __builtin_amdgcn_s_setprio(1);
    #pragma unroll
    for (int ks=0; ks<8; ks++){
      #pragma unroll
      for (int ct=0; ct<2; ct++){
        const int row = 16*ct + lr;
        const s16x8 kf = *(const s16x8*)
            &Klds[row*256 + (((4*ks + lq) ^ (row&31)) << 3)];
        sacc[ct] = __builtin_amdgcn_mfma_f32_16x16x32_bf16(qf[ks], kf, sacc[ct], 0,0,0);
      }
    }
    __builtin_amdgcn_s_setprio(0);
    // P = exp(S*beta); psum partial; pack to per-wave Plds
    #pragma unroll
    for (int ct=0; ct<2; ct++)
      #pragma unroll
      for (int r=0; r<4; r++){
        float be = Bp[(16*w + 4*lq + r)*32 + 16*ct + lr];
        float p = __expf(sacc[ct][r] * be);
        psum[r] += p;
        Pw[(4*lq + r)*40 + 16*ct + lr] = f2bf(p);
      }
    // PV: O[q][c] += P[q][m] V[c][m]   (K=32, one MFMA per ct)
    {
      const s16x8 pf = *(const s16x8*)&Pw[lr*40 + 8*lq];
      __builtin_amdgcn_s_setprio(1);
      #pragma unroll
      for (int ct=0; ct<16; ct++){
        const int c = 16*ct + lr;
        const s16x8 vf = *(const s16x8*)
            &Vt[c*32 + ((lq ^ (c&3)) << 3)];
        oacc[ct] = __builtin_amdgcn_mfma_f32_16x16x32_bf16(pf, vf, oacc[ct], 0,0,0);
      }
      __builtin_amdgcn_s_setprio(0);
    }
    // barrier A: LDS reads done (VMEM queue untouched)
    asm volatile("s_waitcnt lgkmcnt(0)" ::: "memory");
    __builtin_amdgcn_s_barrier();
    if (mt + 1 < 16){
      STAGEK(mb + 32)
      STAGEV(mb + 32)
    }
    __syncthreads();   // drains K/V staging + already-flown beta(t+1)
  }
#undef STAGEK
#undef STAGEV
#undef STAGEB

  // psum reduce over the 16-lane lr group (lanes share (w,lq) -> same q rows)
  #pragma unroll
  for (int r=0;r<4;r++){
    #pragma unroll
    for (int d=1; d<16; d<<=1) psum[r] += __shfl_xor(psum[r], d, 64);
  }
  // store unnormalized bf16 partials
  unsigned short* Ob = Opb + ((size_t)mh*8 + b)*(size_t)N_*C_;
  #pragma unroll
  for (int ct=0; ct<16; ct++){
    const int c = 16*ct + lr;
    #pragma unroll
    for (int r=0; r<4; r++){
      const int qo = nb + 16*w + 4*lq + r;
      Ob[(size_t)qo*C_ + c] = f2bf(oacc[ct][r]);
    }
  }
  if (lr == 0){
    float* Lb = Ls + ((size_t)mh*8 + b)*N_;
    #pragma unroll
    for (int r=0;r<4;r++) Lb[nb + 16*w + 4*lq + r] = psum[r];
  }
}

// ---------------- fused MLP: merge+normalize -> conv1(BN,ReLU) -> conv2(BN,ReLU)
// -> conv3(+bias) -> residual add, all through LDS (overlaid phases).
__global__ __launch_bounds__(256) void k_mlpf(
    const unsigned short* __restrict__ Opb, const float* __restrict__ Ls,
    const unsigned short* __restrict__ W1, const float* __restrict__ sc1,
    const float* __restrict__ sh1,
    const unsigned short* __restrict__ W2, const float* __restrict__ sc2,
    const float* __restrict__ sh2,
    const unsigned short* __restrict__ W3, const float* __restrict__ b3,
    const float* __restrict__ x, float* __restrict__ out)
{
  __shared__ __align__(16) char smem[65792];
  unsigned short* Alds = (unsigned short*)smem;            // [64][256] @0 (phase1)
  unsigned short* H2   = (unsigned short*)(smem + 33024);  // [64][128]
  unsigned short* H1   = (unsigned short*)(smem + 49408);  // [64][128]
  float*          Dlds = (float*)smem;                     // [64][129] (phase3)
  int b = blockIdx.y, nt = blockIdx.x, nb = nt*64;
  int tid = threadIdx.x;
  const size_t PS = (size_t)8*N_*C_;
  for (int i = tid; i < 64*32; i += 256){
    int r = i >> 5, cv = i & 31;
    int row = nb + r;
    float ls = Ls[(size_t)b*N_ + row] + Ls[(size_t)(8+b)*N_ + row]
             + Ls[(size_t)(16+b)*N_ + row] + Ls[(size_t)(24+b)*N_ + row];
    float inv = 1.f / ls;
    size_t base = ((size_t)b*N_ + row)*C_ + cv*8;
    float a8[8] = {0.f,0.f,0.f,0.f,0.f,0.f,0.f,0.f};
    #pragma unroll
    for (int m=0;m<4;m++){
      s16x8 v = *(const s16x8*)&Opb[(size_t)m*PS + base];
      #pragma unroll
      for (int j=0;j<8;j++) a8[j] += bf2f((unsigned short)v[j]);
    }
    s16x8 o;
    #pragma unroll
    for (int j=0;j<8;j++) o[j] = (short)f2bf(a8[j] * inv);
    *(s16x8*)&Alds[r*256 + ((cv*8) ^ ((r&7)<<3))] = o;
  }
  __syncthreads();
  int w = tid >> 6, l = tid & 63, lr = l & 15, lq = l >> 4;
  f32x4 zero = {0.f,0.f,0.f,0.f};
  {
    f32x4 acc[8];
    #pragma unroll
    for (int i=0;i<8;i++) acc[i] = zero;
    #pragma unroll
    for (int ks = 0; ks < 8; ks++){
      s16x8 a = *(const s16x8*)&Alds[(16*w + lr)*256 + ((32*ks + 8*lq) ^ ((lr&7)<<3))];
      #pragma unroll
      for (int ct = 0; ct < 8; ct++){
        s16x8 bw = *(const s16x8*)&W1[(size_t)(16*ct + lr)*C_ + 32*ks + 8*lq];
        acc[ct] = __builtin_amdgcn_mfma_f32_16x16x32_bf16(a, bw, acc[ct], 0, 0, 0);
      }
    }
    __syncthreads();
    #pragma unroll
    for (int ct = 0; ct < 8; ct++){
      int o = 16*ct + lr;
      float s_ = sc1[o], h_ = sh1[o];
      #pragma unroll
      for (int r = 0; r < 4; r++){
        int row = 16*w + 4*lq + r;
        H1[row*128 + (o ^ ((row&7)<<3))] = f2bf(fmaxf(acc[ct][r]*s_ + h_, 0.f));
      }
    }
  }
  __syncthreads();
  {
    f32x4 acc[8];
    #pragma unroll
    for (int i=0;i<8;i++) acc[i] = zero;
    #pragma unroll
    for (int ks = 0; ks < 4; ks++){
      s16x8 a = *(const s16x8*)&H1[(16*w + lr)*128 + ((32*ks + 8*lq) ^ ((lr&7)<<3))];
      #pragma unroll
      for (int ct = 0; ct < 8; ct++){
        s16x8 bw = *(const s16x8*)&W2[(size_t)(16*ct + lr)*HC + 32*ks + 8*lq];
        acc[ct] = __builtin_amdgcn_mfma_f32_16x16x32_bf16(a, bw, acc[ct], 0, 0, 0);
      }
    }
    __syncthreads();
    #pragma unroll
    for (int ct = 0; ct < 8; ct++){
      int o = 16*ct + lr;
      float s_ = sc2[o], h_ = sh2[o];
      #pragma unroll
      for (int r = 0; r < 4; r++){
        int row = 16*w + 4*lq + r;
        H2[row*128 + (o ^ ((row&7)<<3))] = f2bf(fmaxf(acc[ct][r]*s_ + h_, 0.f));
      }
    }
  }
  __syncthreads();
  f32x4 acc[16];
  #pragma unroll
  for (int i=0;i<16;i++) acc[i] = zero;
  #pragma unroll
  for (int ks = 0; ks < 4; ks++){
    s16x8 a = *(const s16x8*)&H2[(16*w + lr)*128 + ((32*ks + 8*lq) ^ ((lr&7)<<3))];
    #pragma unroll
    for (int ct = 0; ct < 16; ct++){
      s16x8 bw = *(const s16x8*)&W3[(size_t)(16*ct + lr)*HC + 32*ks + 8*lq];
      acc[ct] = __builtin_amdgcn_mfma_f32_16x16x32_bf16(a, bw, acc[ct], 0, 0, 0);
    }
  }
  const float* xb = x + (size_t)b*C_*N_;
  float* ob = out + (size_t)b*C_*N_;
  int j = tid & 63, o0 = tid >> 6;
  #pragma unroll
  for (int half = 0; half < 2; half++){
    __syncthreads();
    #pragma unroll
    for (int ct = 8*half; ct < 8*half+8; ct++){
      int o = 16*ct + lr;
      float bi = b3[o];
      #pragma unroll
      for (int r = 0; r < 4; r++){
        int row = 16*w + 4*lq + r;
        Dlds[row*129 + (o - 128*half)] = acc[ct][r] + bi;
      }
    }
    __syncthreads();
    for (int o = 128*half + o0; o < 128*half + 128; o += 4)
      ob[(size_t)o*N_ + nb + j] = xb[(size_t)o*N_ + nb + j]
                                + Dlds[j*129 + (o - 128*half)];
  }
}

extern "C" void kernel_launch(void* const* d_in, const int* in_sizes, int n_in,
                              void* d_out, int out_size, void* d_ws, size_t ws_size,
                              hipStream_t stream)
{
  const float* x    = (const float*)d_in[0];
  const float* beta = (const float*)d_in[1];
  const float* wq = (const float*)d_in[2];  const float* bq = (const float*)d_in[3];
  const float* wk = (const float*)d_in[4];  const float* bk = (const float*)d_in[5];
  const float* wv = (const float*)d_in[6];  const float* bv = (const float*)d_in[7];
  const float* w1 = (const float*)d_in[8];  const float* b1 = (const float*)d_in[9];
  const float* g1 = (const float*)d_in[10]; const float* be1= (const float*)d_in[11];
  const float* m1 = (const float*)d_in[12]; const float* v1 = (const float*)d_in[13];
  const float* w2 = (const float*)d_in[14]; const float* b2 = (const float*)d_in[15];
  const float* g2 = (const float*)d_in[16]; const float* be2= (const float*)d_in[17];
  const float* m2 = (const float*)d_in[18]; const float* v2 = (const float*)d_in[19];
  const float* w3 = (const float*)d_in[20]; const float* b3 = (const float*)d_in[21];

  char* p = (char*)d_ws;
  auto alloc = [&](size_t n){ char* r = p; p += (n + 255) & ~(size_t)255; return r; };
  unsigned short* Qn  = (unsigned short*)alloc((size_t)B_*N_*C_*2);
  unsigned short* Kn  = (unsigned short*)alloc((size_t)B_*N_*C_*2);
  unsigned short* Vc  = (unsigned short*)alloc((size_t)B_*N_*C_*2);
  unsigned short* Opb = (unsigned short*)alloc((size_t)4*B_*N_*C_*2);
  float* Ls = (float*)alloc((size_t)4*B_*N_*4);
  unsigned short* wqb = (unsigned short*)alloc(65536*2);
  unsigned short* wkb = (unsigned short*)alloc(65536*2);
  unsigned short* wvb = (unsigned short*)alloc(65536*2);
  unsigned short* w1b = (unsigned short*)alloc(32768*2);
  unsigned short* w2b = (unsigned short*)alloc(16384*2);
  unsigned short* w3b = (unsigned short*)alloc(32768*2);
  float* sc1 = (float*)alloc(128*4);
  float* sh1 = (float*)alloc(128*4);
  float* sc2 = (float*)alloc(128*4);
  float* sh2 = (float*)alloc(128*4);

  PrepArgs pa;
  pa.s0 = wq; pa.s1 = wk; pa.s2 = wv; pa.s3 = w1; pa.s4 = w2; pa.s5 = w3;
  pa.d0 = wqb; pa.d1 = wkb; pa.d2 = wvb; pa.d3 = w1b; pa.d4 = w2b; pa.d5 = w3b;
  pa.b1 = b1; pa.g1 = g1; pa.be1 = be1; pa.m1 = m1; pa.v1 = v1;
  pa.b2 = b2; pa.g2 = g2; pa.be2 = be2; pa.m2 = m2; pa.v2 = v2;
  pa.sc1 = sc1; pa.sh1 = sh1; pa.sc2 = sc2; pa.sh2 = sh2;

  k_prep<<<dim3(1089), dim3(256), 0, stream>>>(pa);
  k_qkv<<<dim3(32, 8, 3), dim3(256), 0, stream>>>(x, wqb, wkb, wvb, bq, bk, bv, Qn, Kn, Vc);
  k_attn<<<dim3(1024), dim3(256), 0, stream>>>(Qn, Kn, Vc, beta, Opb, Ls);
  k_mlpf<<<dim3(32, 8), dim3(256), 0, stream>>>(Opb, Ls, w1b, sc1, sh1,
                                                w2b, sc2, sh2, w3b, b3,
                                                x, (float*)d_out);
}